// Round 5
// baseline (85.812 us; speedup 1.0000x reference)
//
#include <hip/hip_runtime.h>

// out[1024][1024] = relu(a @ feats^T) @ relu(b @ feats^T)^T
//   a,b: [1024][2048] fp32, feats: [128][2048] fp32, out fp32.
// Pipeline (2 dispatches):
//   gemm1_part8: grid (64,8) = 32-row M-stripes x 8 K-splits (K=256 each, 4
//                iters of 64) -> fp32 partials part[8][2048][128] (8 MB)
//   gemm2_fused: 64x64 out tiles; staging sums the 8 fp32 partials from
//                L2/L3, applies relu, converts to bf16 in LDS, then MFMA.
// Lessons: grid.sync (R1) and atomics (R2) cost more than a dispatch; serial
// K-chain must stay short (R3); ~44 us ws poison-fill is a fixed floor term.

typedef __attribute__((ext_vector_type(8))) __bf16 bf16x8;
typedef __attribute__((ext_vector_type(4))) __bf16 bf16x4;
typedef __attribute__((ext_vector_type(4))) float floatx4;

#define KD     2048   // inner K of gemm1
#define NF     128    // feature count = K of gemm2
#define NA     1024   // rows of a (= rows of b = out dim)
#define NPART  8      // K-splits (K=256 each)
#define KSL    256    // K per split
#define FKN    (2048 * 128)

static __device__ inline bf16x8 cvt8(float4 u, float4 v) {
    bf16x8 s;
    s[0] = (__bf16)u.x; s[1] = (__bf16)u.y; s[2] = (__bf16)u.z; s[3] = (__bf16)u.w;
    s[4] = (__bf16)v.x; s[5] = (__bf16)v.y; s[6] = (__bf16)v.z; s[7] = (__bf16)v.w;
    return s;
}

// ---- gemm1_part8: part[s][m0:m0+32][0:128] = X[m0:m0+32, s*256:(s+1)*256] . feats^T
// block = 4 waves; wave w covers feat-cols [w*32, w*32+32). 4 K-iters of 64.
__global__ __launch_bounds__(256) void gemm1_part8(const float* __restrict__ A,
                                                   const float* __restrict__ B,
                                                   const float* __restrict__ F,
                                                   float* __restrict__ part) {
    __shared__ __bf16 Xs[32 * 72];    // 32 rows x 64 K-cols, stride 72
    __shared__ __bf16 Fs[128 * 72];   // 128 feat-rows x 64 K-cols

    const int t    = threadIdx.x;
    const int m0   = blockIdx.x * 32;
    const int s    = blockIdx.y;
    const int k0   = s * KSL;
    const float* src = (m0 < NA) ? (A + (size_t)m0 * KD)
                                 : (B + (size_t)(m0 - NA) * KD);

    const int lane = t & 63;
    const int w    = t >> 6;
    const int ln   = lane & 15;
    const int quad = lane >> 4;
    const int q8   = quad * 8;

    floatx4 acc[2][2];
#pragma unroll
    for (int mt = 0; mt < 2; mt++)
#pragma unroll
        for (int nt = 0; nt < 2; nt++)
            acc[mt][nt] = (floatx4){0.f, 0.f, 0.f, 0.f};

    const int xrow = t >> 3, xcol = (t & 7) * 8;    // 32 rows x 64 cols, 8 floats/thr
    const int frow = t >> 1, fcol = (t & 1) * 32;   // 128 rows x 64 cols, 32 floats/thr
    const float* xp = src + (size_t)xrow * KD + (k0 + xcol);
    const float* fp = F   + (size_t)frow * KD + (k0 + fcol);

    // register prefetch of kk=0
    float4 xa = *(const float4*)(xp + 0);
    float4 xb = *(const float4*)(xp + 4);
    float4 fa[8];
#pragma unroll
    for (int i = 0; i < 8; i++) fa[i] = *(const float4*)(fp + 4 * i);

#pragma unroll
    for (int kk = 0; kk < KSL; kk += 64) {
        *(bf16x8*)&Xs[xrow * 72 + xcol] = cvt8(xa, xb);
#pragma unroll
        for (int i = 0; i < 4; i++)
            *(bf16x8*)&Fs[frow * 72 + fcol + 8 * i] = cvt8(fa[2 * i], fa[2 * i + 1]);
        __syncthreads();

        if (kk + 64 < KSL) {   // prefetch next K-chunk while MFMAs run
            xa = *(const float4*)(xp + kk + 64);
            xb = *(const float4*)(xp + kk + 68);
#pragma unroll
            for (int i = 0; i < 8; i++)
                fa[i] = *(const float4*)(fp + kk + 64 + 4 * i);
        }

#pragma unroll
        for (int sub = 0; sub < 64; sub += 32) {
            bf16x8 bfrag[2];
#pragma unroll
            for (int nt = 0; nt < 2; nt++)
                bfrag[nt] = *(const bf16x8*)&Fs[(w * 32 + nt * 16 + ln) * 72 + sub + q8];
#pragma unroll
            for (int mt = 0; mt < 2; mt++) {
                bf16x8 af = *(const bf16x8*)&Xs[(mt * 16 + ln) * 72 + sub + q8];
#pragma unroll
                for (int nt = 0; nt < 2; nt++)
                    acc[mt][nt] = __builtin_amdgcn_mfma_f32_16x16x32_bf16(
                        af, bfrag[nt], acc[mt][nt], 0, 0, 0);
            }
        }
        __syncthreads();
    }

    float* pdst = part + (size_t)s * FKN;
#pragma unroll
    for (int mt = 0; mt < 2; mt++)
#pragma unroll
        for (int nt = 0; nt < 2; nt++)
#pragma unroll
            for (int r = 0; r < 4; r++) {
                int row = m0 + mt * 16 + quad * 4 + r;
                int col = w * 32 + nt * 16 + ln;
                pdst[(size_t)row * NF + col] = acc[mt][nt][r];
            }
}

// ---- gemm2_fused: out[i][j] = sum_f relu(sum_s part[s][i][f]) * relu(sum_s part[s][1024+j][f])
// grid (16,16): 64x64 out tiles; block = 4 waves in 2x2. Staging does the
// 8-partial fp32 reduce + relu + bf16 cvt inline (partials are L2-resident).
__global__ __launch_bounds__(256) void gemm2_fused(const float* __restrict__ part,
                                                   float* __restrict__ out) {
    __shared__ __bf16 Ps[64 * 136];
    __shared__ __bf16 Qs[64 * 136];

    const int t    = threadIdx.x;
    const int i0   = blockIdx.y * 64;
    const int j0   = blockIdx.x * 64;
    const int lane = t & 63;
    const int w    = t >> 6;
    const int wm   = w & 1;
    const int wn   = w >> 1;
    const int ln   = lane & 15;
    const int quad = lane >> 4;
    const int q8   = quad * 8;

    // stage: 64 rows x 128 cols each = 2048 float4-groups per matrix;
    // thread t handles groups {g*256+t}, coalesced float4 reads per split.
#pragma unroll
    for (int g = 0; g < 8; g++) {
        const int idx4 = g * 256 + t;
        const int row  = idx4 >> 5;          // 0..63
        const int col  = (idx4 & 31) * 4;    // 0..124
        const float* p = part + (size_t)(i0 + row) * NF + col;
        const float* q = part + (size_t)(NA + j0 + row) * NF + col;
        float4 sp = make_float4(0.f, 0.f, 0.f, 0.f);
        float4 sq = make_float4(0.f, 0.f, 0.f, 0.f);
#pragma unroll
        for (int s = 0; s < NPART; s++) {
            float4 u = *(const float4*)(p + (size_t)s * FKN);
            float4 v = *(const float4*)(q + (size_t)s * FKN);
            sp.x += u.x; sp.y += u.y; sp.z += u.z; sp.w += u.w;
            sq.x += v.x; sq.y += v.y; sq.z += v.z; sq.w += v.w;
        }
        bf16x4 op, oq;
        op[0] = (__bf16)fmaxf(sp.x, 0.f); op[1] = (__bf16)fmaxf(sp.y, 0.f);
        op[2] = (__bf16)fmaxf(sp.z, 0.f); op[3] = (__bf16)fmaxf(sp.w, 0.f);
        oq[0] = (__bf16)fmaxf(sq.x, 0.f); oq[1] = (__bf16)fmaxf(sq.y, 0.f);
        oq[2] = (__bf16)fmaxf(sq.z, 0.f); oq[3] = (__bf16)fmaxf(sq.w, 0.f);
        *(bf16x4*)&Ps[row * 136 + col] = op;
        *(bf16x4*)&Qs[row * 136 + col] = oq;
    }
    __syncthreads();

    floatx4 acc[2][2];
#pragma unroll
    for (int mt = 0; mt < 2; mt++)
#pragma unroll
        for (int nt = 0; nt < 2; nt++)
            acc[mt][nt] = (floatx4){0.f, 0.f, 0.f, 0.f};

#pragma unroll
    for (int k0 = 0; k0 < 128; k0 += 32) {
        bf16x8 af[2], bf[2];
#pragma unroll
        for (int mt = 0; mt < 2; mt++)
            af[mt] = *(const bf16x8*)&Ps[(wm * 32 + mt * 16 + ln) * 136 + k0 + q8];
#pragma unroll
        for (int nt = 0; nt < 2; nt++)
            bf[nt] = *(const bf16x8*)&Qs[(wn * 32 + nt * 16 + ln) * 136 + k0 + q8];
#pragma unroll
        for (int mt = 0; mt < 2; mt++)
#pragma unroll
            for (int nt = 0; nt < 2; nt++)
                acc[mt][nt] = __builtin_amdgcn_mfma_f32_16x16x32_bf16(
                    af[mt], bf[nt], acc[mt][nt], 0, 0, 0);
    }

#pragma unroll
    for (int mt = 0; mt < 2; mt++)
#pragma unroll
        for (int nt = 0; nt < 2; nt++)
#pragma unroll
            for (int r = 0; r < 4; r++) {
                int row = i0 + wm * 32 + mt * 16 + quad * 4 + r;
                int col = j0 + wn * 32 + nt * 16 + ln;
                out[(size_t)row * 1024 + col] = acc[mt][nt][r];
            }
}

extern "C" void kernel_launch(void* const* d_in, const int* in_sizes, int n_in,
                              void* d_out, int out_size, void* d_ws, size_t ws_size,
                              hipStream_t stream) {
    const float* a     = (const float*)d_in[0];
    const float* b     = (const float*)d_in[1];
    const float* feats = (const float*)d_in[2];
    float* out = (float*)d_out;

    float* part = (float*)d_ws;   // 8 MB fp32 partials

    gemm1_part8<<<dim3(64, NPART), 256, 0, stream>>>(a, b, feats, part);
    gemm2_fused<<<dim3(16, 16), 256, 0, stream>>>(part, out);
}